// Round 4
// baseline (223.442 us; speedup 1.0000x reference)
//
#include <hip/hip_runtime.h>
#include <math.h>

#define N_NODES 100000
#define N_EDGES 1600000
#define IN_DIM  256
#define HIDDEN  64

// ---- edge chunking: 32 chunks of 50000 edges; grids = chunks x ranges -------
#define NB      32          // edge chunks
#define EPB     50000       // edges per chunk (NB*EPB == N_EDGES)
#define QPB     12500       // int4 groups per chunk
// scatter: 8 node ranges of 12544 (LDS 50,176 B); grid 32x8 = 256 = 1/CU
#define SR      8
#define SRANGE  12544
// degree: 8 node ranges of 12800, byte-packed u32 (LDS 12,800 B); grid 256
#define PD      8
#define DNR     12800
#define DW      3200        // DNR/4 packed words

// ---------------------------------------------------------------------------
// K1: v[i] = sum_j W[i][j]*w2[j];  c = b.w2 + b2   (collapse hidden dim)
// ---------------------------------------------------------------------------
__global__ void wv_kernel(const float* __restrict__ W, const float* __restrict__ b,
                          const float* __restrict__ w2, const float* __restrict__ b2,
                          float* __restrict__ v, float* __restrict__ c) {
    int i = threadIdx.x;  // 256 threads
    float acc = 0.f;
    #pragma unroll 8
    for (int j = 0; j < HIDDEN; ++j) acc += W[i * HIDDEN + j] * w2[j];
    v[i] = acc;
    if (i == 0) {
        float cc = b2[0];
        for (int j = 0; j < HIDDEN; ++j) cc += b[j] * w2[j];
        *c = cc;
    }
}

// ---------------------------------------------------------------------------
// K2: s[n] = x[n] . v  — one wave per node row (64 lanes x float4 = 1 KiB row)
// ---------------------------------------------------------------------------
__global__ void s_kernel(const float* __restrict__ x, const float* __restrict__ v,
                         float* __restrict__ s) {
    const int wave = threadIdx.x >> 6;
    const int lane = threadIdx.x & 63;
    const int n = blockIdx.x * 4 + wave;   // grid = 25000 -> exactly N
    const float4* xr = (const float4*)(x + (size_t)n * IN_DIM);
    const float4* vr = (const float4*)v;
    float4 a  = xr[lane];
    float4 vv = vr[lane];
    float d = a.x * vv.x + a.y * vv.y + a.z * vv.z + a.w * vv.w;
    #pragma unroll
    for (int off = 32; off > 0; off >>= 1) d += __shfl_down(d, off, 64);
    if (lane == 0) s[n] = d;
}

// ---------------------------------------------------------------------------
// K3: degree histogram, byte-packed, grid = 32 chunks x 8 ranges.
// Per-chunk per-node count ~ Poisson(0.5) << 256 — no byte overflow.
// ---------------------------------------------------------------------------
__global__ void __launch_bounds__(512) deg_hist_kernel(const int4* __restrict__ dst4,
                                                       unsigned* __restrict__ partialD) {
    __shared__ unsigned hist[DW];
    const int r  = blockIdx.x & (PD - 1);
    const int bb = blockIdx.x >> 3;            // PD == 8
    const int nbase = r * DNR;
    for (int i = threadIdx.x; i < DW; i += 512) hist[i] = 0u;
    __syncthreads();
    const int q0 = bb * QPB;
    for (int k = threadIdx.x; k < QPB; k += 512) {
        int4 d4 = dst4[q0 + k];
        int d0 = d4.x - nbase, d1 = d4.y - nbase, d2 = d4.z - nbase, d3 = d4.w - nbase;
        if ((unsigned)d0 < (unsigned)DNR) atomicAdd(&hist[d0 >> 2], 1u << ((d0 & 3) * 8));
        if ((unsigned)d1 < (unsigned)DNR) atomicAdd(&hist[d1 >> 2], 1u << ((d1 & 3) * 8));
        if ((unsigned)d2 < (unsigned)DNR) atomicAdd(&hist[d2 >> 2], 1u << ((d2 & 3) * 8));
        if ((unsigned)d3 < (unsigned)DNR) atomicAdd(&hist[d3 >> 2], 1u << ((d3 & 3) * 8));
    }
    __syncthreads();
    unsigned* outp = partialD + (size_t)blockIdx.x * DW;  // (bb*PD + r) * DW
    for (int i = threadIdx.x; i < DW; i += 512) outp[i] = hist[i];
}

// ---------------------------------------------------------------------------
// K4: merge byte-packed partials -> deg; fuse dinv = rsqrt(deg+1), t = dinv*s.
// One thread per packed word (4 nodes). Coalesced over j.
// ---------------------------------------------------------------------------
__global__ void deg_merge_kernel(const unsigned* __restrict__ partialD,
                                 const float* __restrict__ s,
                                 float* __restrict__ dinv, float* __restrict__ t) {
    int w = blockIdx.x * blockDim.x + threadIdx.x;
    if (w >= N_NODES / 4) return;              // 25000 words cover all nodes
    const int r = w / DW, j = w - r * DW;
    unsigned a0 = 0, a1 = 0, a2 = 0, a3 = 0;
    #pragma unroll 8
    for (int b = 0; b < NB; ++b) {
        unsigned p = partialD[(size_t)(b * PD + r) * DW + j];
        a0 += p & 255u; a1 += (p >> 8) & 255u; a2 += (p >> 16) & 255u; a3 += p >> 24;
    }
    const int n0 = w * 4;                      // == r*DNR + j*4
    float4 sv = *(const float4*)(s + n0);
    float4 di, tv;
    di.x = rsqrtf((float)(a0 + 1)); di.y = rsqrtf((float)(a1 + 1));
    di.z = rsqrtf((float)(a2 + 1)); di.w = rsqrtf((float)(a3 + 1));
    tv.x = di.x * sv.x; tv.y = di.y * sv.y; tv.z = di.z * sv.z; tv.w = di.w * sv.w;
    *(float4*)(dinv + n0) = di;
    *(float4*)(t + n0) = tv;
}

// ---------------------------------------------------------------------------
// K5: scatter u[dst] += t[src] via LDS-private accumulators.
// grid = 32 chunks x 8 ranges = 256 blocks (one per CU, all co-resident).
// ---------------------------------------------------------------------------
__global__ void __launch_bounds__(512) scat_hist_kernel(const int4* __restrict__ src4,
                                                        const int4* __restrict__ dst4,
                                                        const float* __restrict__ t,
                                                        float* __restrict__ partialU) {
    __shared__ float acc[SRANGE];
    const int r  = blockIdx.x & (SR - 1);
    const int bb = blockIdx.x >> 3;            // SR == 8
    const int nbase = r * SRANGE;
    for (int i = threadIdx.x; i < SRANGE; i += 512) acc[i] = 0.f;
    __syncthreads();
    const int q0 = bb * QPB;
    for (int k = threadIdx.x; k < QPB; k += 512) {
        int4 d4 = dst4[q0 + k];
        int4 s4 = src4[q0 + k];
        int d0 = d4.x - nbase, d1 = d4.y - nbase, d2 = d4.z - nbase, d3 = d4.w - nbase;
        if ((unsigned)d0 < (unsigned)SRANGE) atomicAdd(&acc[d0], t[s4.x]);
        if ((unsigned)d1 < (unsigned)SRANGE) atomicAdd(&acc[d1], t[s4.y]);
        if ((unsigned)d2 < (unsigned)SRANGE) atomicAdd(&acc[d2], t[s4.z]);
        if ((unsigned)d3 < (unsigned)SRANGE) atomicAdd(&acc[d3], t[s4.w]);
    }
    __syncthreads();
    float* outp = partialU + (size_t)blockIdx.x * SRANGE;  // (bb*SR + r) * SRANGE
    for (int i = threadIdx.x; i < SRANGE; i += 512) outp[i] = acc[i];
}

// ---------------------------------------------------------------------------
// K6: merge scatter partials + sigmoid epilogue.
// ---------------------------------------------------------------------------
__global__ void merge_final_kernel(const float* __restrict__ partialU,
                                   const float* __restrict__ dinv,
                                   const float* __restrict__ s,
                                   const float* __restrict__ c,
                                   float* __restrict__ out) {
    int n = blockIdx.x * blockDim.x + threadIdx.x;
    if (n >= N_NODES) return;
    const int r = n / SRANGE, j = n - r * SRANGE;
    float u = 0.f;
    #pragma unroll 8
    for (int b = 0; b < NB; ++b)
        u += partialU[(size_t)(b * SR + r) * SRANGE + j];
    float di = dinv[n];
    float pre = di * (u + di * s[n]) + c[0];
    out[n] = 1.f / (1.f + expf(-pre));
}

// ------------------------- fallback path (R1, validated) --------------------
__global__ void deg_kernel(const int* __restrict__ dst, int* __restrict__ cnt) {
    int e = blockIdx.x * blockDim.x + threadIdx.x;
    if (e < N_EDGES) atomicAdd(&cnt[dst[e]], 1);
}
__global__ void dinv_kernel(const int* __restrict__ cnt, const float* __restrict__ s,
                            float* __restrict__ dinv, float* __restrict__ t) {
    int n = blockIdx.x * blockDim.x + threadIdx.x;
    if (n < N_NODES) {
        float di = rsqrtf((float)(cnt[n] + 1));
        dinv[n] = di;
        t[n] = di * s[n];
    }
}
__global__ void scatter_kernel(const int* __restrict__ src, const int* __restrict__ dst,
                               const float* __restrict__ t, float* __restrict__ u) {
    int e = blockIdx.x * blockDim.x + threadIdx.x;
    if (e < N_EDGES) atomicAdd(&u[dst[e]], t[src[e]]);
}
__global__ void final_kernel(const float* __restrict__ dinv, const float* __restrict__ u,
                             const float* __restrict__ s, const float* __restrict__ c,
                             float* __restrict__ out) {
    int n = blockIdx.x * blockDim.x + threadIdx.x;
    if (n < N_NODES) {
        float di = dinv[n];
        float pre = di * (u[n] + di * s[n]) + c[0];
        out[n] = 1.f / (1.f + expf(-pre));
    }
}
// ----------------------------------------------------------------------------

extern "C" void kernel_launch(void* const* d_in, const int* in_sizes, int n_in,
                              void* d_out, int out_size, void* d_ws, size_t ws_size,
                              hipStream_t stream) {
    const float* x   = (const float*)d_in[0];   // [N, 256]
    const int*   ei  = (const int*)  d_in[1];   // [2, E]: src then dst
    const float* W   = (const float*)d_in[2];   // [256, 64]
    const float* b   = (const float*)d_in[3];   // [64]
    const float* w2  = (const float*)d_in[4];   // [64]
    const float* b2  = (const float*)d_in[5];   // [1]
    float* out = (float*)d_out;

    const int* src = ei;
    const int* dst = ei + N_EDGES;

    float* ws   = (float*)d_ws;
    float*    v        = ws + 0;        // 256
    float*    c        = ws + 256;      // 1
    float*    s        = ws + 512;      // 100000
    float*    t        = ws + 100608;   // 100000
    float*    dinv     = ws + 200704;   // 100000
    unsigned* partialD = (unsigned*)(ws + 300800);  // 32*8*3200  =   819,200 words (3.3 MB)
    float*    partialU = ws + 1120000;              // 32*8*12544 = 3,211,264 floats (12.8 MB)
    const size_t need_bytes = (size_t)(1120000 + NB * SR * SRANGE) * 4;  // 17.3 MB

    wv_kernel<<<1, 256, 0, stream>>>(W, b, w2, b2, v, c);
    s_kernel<<<N_NODES / 4, 256, 0, stream>>>(x, v, s);

    if (ws_size >= need_bytes) {
        deg_hist_kernel<<<NB * PD, 512, 0, stream>>>((const int4*)dst, partialD);
        deg_merge_kernel<<<(N_NODES / 4 + 255) / 256, 256, 0, stream>>>(partialD, s, dinv, t);
        scat_hist_kernel<<<NB * SR, 512, 0, stream>>>((const int4*)src, (const int4*)dst, t, partialU);
        merge_final_kernel<<<(N_NODES + 511) / 512, 512, 0, stream>>>(partialU, dinv, s, c, out);
    } else {
        // fallback: validated device-atomic path (needs zeroed u/cnt)
        float* u   = ws + 300800;
        int*   cnt = (int*)(ws + 400800);
        hipMemsetAsync((char*)d_ws + (size_t)300800 * 4, 0, (size_t)200000 * 4, stream);
        deg_kernel<<<(N_EDGES + 255) / 256, 256, 0, stream>>>(dst, cnt);
        dinv_kernel<<<(N_NODES + 255) / 256, 256, 0, stream>>>(cnt, s, dinv, t);
        scatter_kernel<<<(N_EDGES + 255) / 256, 256, 0, stream>>>(src, dst, t, u);
        final_kernel<<<(N_NODES + 255) / 256, 256, 0, stream>>>(dinv, u, s, c, out);
    }
}

// Round 5
// 207.179 us; speedup vs baseline: 1.0785x; 1.0785x over previous
//
#include <hip/hip_runtime.h>
#include <math.h>

#define N_NODES 100000
#define N_EDGES 1600000
#define IN_DIM  256
#define HIDDEN  64

// ---- edge chunking: 32 chunks of 50000 edges ------------------------------
#define NB      32          // edge chunks
#define EPB     50000       // edges per chunk (NB*EPB == N_EDGES)
#define QPB     12500       // int4 groups per chunk
// scatter: 8 node ranges of 12544 (LDS 50,176 B); grid 32x8 = 256 blocks
#define SR      8
#define SRANGE  12544
// degree: 8 node ranges of 12800, byte-packed u32 (LDS 12.8 KB); 256 blocks
#define PD      8
#define DNR     12800
#define DW      3200        // DNR/4 packed words
#define DEGB    256         // deg blocks in fused kernel (== NB*PD)

// ---------------------------------------------------------------------------
// K_A (fused): blocks [0,DEGB) build byte-packed degree histograms;
// blocks [DEGB, DEGB+256) compute v = W.w2 in LDS then s[n] = x[n].v
// (one wave per row; 64 lanes x float4 = full 1 KiB row).
// deg (L2/LDS-bound) and s (HBM-bound) overlap on different CUs.
// ---------------------------------------------------------------------------
__global__ void __launch_bounds__(1024) fusedA_kernel(const float* __restrict__ x,
                                                      const float* __restrict__ W,
                                                      const float* __restrict__ w2,
                                                      const int4* __restrict__ dst4,
                                                      unsigned* __restrict__ partialD,
                                                      float* __restrict__ s) {
    __shared__ __align__(16) unsigned sh[DW];
    const int bid = blockIdx.x;
    if (bid < DEGB) {
        // ---- degree histogram: chunk bb, range r ----
        const int r  = bid & (PD - 1);
        const int bb = bid >> 3;
        const int nbase = r * DNR;
        for (int i = threadIdx.x; i < DW; i += 1024) sh[i] = 0u;
        __syncthreads();
        const int q0 = bb * QPB;
        for (int k = threadIdx.x; k < QPB; k += 1024) {
            int4 d4 = dst4[q0 + k];
            int d0 = d4.x - nbase, d1 = d4.y - nbase, d2 = d4.z - nbase, d3 = d4.w - nbase;
            if ((unsigned)d0 < (unsigned)DNR) atomicAdd(&sh[d0 >> 2], 1u << ((d0 & 3) * 8));
            if ((unsigned)d1 < (unsigned)DNR) atomicAdd(&sh[d1 >> 2], 1u << ((d1 & 3) * 8));
            if ((unsigned)d2 < (unsigned)DNR) atomicAdd(&sh[d2 >> 2], 1u << ((d2 & 3) * 8));
            if ((unsigned)d3 < (unsigned)DNR) atomicAdd(&sh[d3 >> 2], 1u << ((d3 & 3) * 8));
        }
        __syncthreads();
        unsigned* outp = partialD + (size_t)bid * DW;
        for (int i = threadIdx.x; i < DW; i += 1024) outp[i] = sh[i];
    } else {
        // ---- s = x @ v, v computed in-block (W is L2-hot: 64KB x 256 blocks) ----
        float* vsh = (float*)sh;
        if (threadIdx.x < IN_DIM) {
            const float4* wr  = (const float4*)(W + threadIdx.x * HIDDEN);
            const float4* w2r = (const float4*)w2;
            float acc = 0.f;
            #pragma unroll
            for (int j = 0; j < HIDDEN / 4; ++j) {
                float4 a = wr[j], q = w2r[j];
                acc += a.x * q.x + a.y * q.y + a.z * q.z + a.w * q.w;
            }
            vsh[threadIdx.x] = acc;
        }
        __syncthreads();
        const int wid  = threadIdx.x >> 6;
        const int lane = threadIdx.x & 63;
        const int gw   = (bid - DEGB) * 16 + wid;      // 0..4095
        float4 vv = ((const float4*)vsh)[lane];
        for (int n = gw; n < N_NODES; n += 4096) {
            const float4* xr = (const float4*)(x + (size_t)n * IN_DIM);
            float4 a = xr[lane];
            float d = a.x * vv.x + a.y * vv.y + a.z * vv.z + a.w * vv.w;
            #pragma unroll
            for (int off = 32; off > 0; off >>= 1) d += __shfl_down(d, off, 64);
            if (lane == 0) s[n] = d;
        }
    }
}

// ---------------------------------------------------------------------------
// K_B: merge byte-packed degree partials; fuse dinv = rsqrt(deg+1), t = dinv*s.
// ---------------------------------------------------------------------------
__global__ void deg_merge_kernel(const unsigned* __restrict__ partialD,
                                 const float* __restrict__ s,
                                 float* __restrict__ dinv, float* __restrict__ t) {
    int w = blockIdx.x * blockDim.x + threadIdx.x;
    if (w >= N_NODES / 4) return;              // 25000 words cover all nodes
    const int r = w / DW, j = w - r * DW;
    unsigned a0 = 0, a1 = 0, a2 = 0, a3 = 0;
    #pragma unroll 8
    for (int b = 0; b < NB; ++b) {
        unsigned p = partialD[(size_t)(b * PD + r) * DW + j];
        a0 += p & 255u; a1 += (p >> 8) & 255u; a2 += (p >> 16) & 255u; a3 += p >> 24;
    }
    const int n0 = w * 4;                      // == r*DNR + j*4
    float4 sv = *(const float4*)(s + n0);
    float4 di, tv;
    di.x = rsqrtf((float)(a0 + 1)); di.y = rsqrtf((float)(a1 + 1));
    di.z = rsqrtf((float)(a2 + 1)); di.w = rsqrtf((float)(a3 + 1));
    tv.x = di.x * sv.x; tv.y = di.y * sv.y; tv.z = di.z * sv.z; tv.w = di.w * sv.w;
    *(float4*)(dinv + n0) = di;
    *(float4*)(t + n0) = tv;
}

// ---------------------------------------------------------------------------
// K_C: scatter u[dst] += t[src] via LDS-private accumulators.
// 256 blocks x 1024 threads = 16 waves/CU for gather-latency hiding.
// ---------------------------------------------------------------------------
__global__ void __launch_bounds__(1024) scat_hist_kernel(const int4* __restrict__ src4,
                                                         const int4* __restrict__ dst4,
                                                         const float* __restrict__ t,
                                                         float* __restrict__ partialU) {
    __shared__ float acc[SRANGE];
    const int r  = blockIdx.x & (SR - 1);
    const int bb = blockIdx.x >> 3;            // SR == 8
    const int nbase = r * SRANGE;
    for (int i = threadIdx.x; i < SRANGE; i += 1024) acc[i] = 0.f;
    __syncthreads();
    const int q0 = bb * QPB;
    for (int k = threadIdx.x; k < QPB; k += 1024) {
        int4 d4 = dst4[q0 + k];
        int4 s4 = src4[q0 + k];
        int d0 = d4.x - nbase, d1 = d4.y - nbase, d2 = d4.z - nbase, d3 = d4.w - nbase;
        if ((unsigned)d0 < (unsigned)SRANGE) atomicAdd(&acc[d0], t[s4.x]);
        if ((unsigned)d1 < (unsigned)SRANGE) atomicAdd(&acc[d1], t[s4.y]);
        if ((unsigned)d2 < (unsigned)SRANGE) atomicAdd(&acc[d2], t[s4.z]);
        if ((unsigned)d3 < (unsigned)SRANGE) atomicAdd(&acc[d3], t[s4.w]);
    }
    __syncthreads();
    float* outp = partialU + (size_t)blockIdx.x * SRANGE;  // (bb*SR + r) * SRANGE
    for (int i = threadIdx.x; i < SRANGE; i += 1024) outp[i] = acc[i];
}

// ---------------------------------------------------------------------------
// K_D: merge scatter partials + sigmoid epilogue; c = b.w2 + b2 inlined
// (uniform scalar loads, negligible).
// ---------------------------------------------------------------------------
__global__ void merge_final_kernel(const float* __restrict__ partialU,
                                   const float* __restrict__ dinv,
                                   const float* __restrict__ s,
                                   const float* __restrict__ b,
                                   const float* __restrict__ w2,
                                   const float* __restrict__ b2,
                                   float* __restrict__ out) {
    float c = b2[0];
    #pragma unroll 8
    for (int j = 0; j < HIDDEN; ++j) c += b[j] * w2[j];
    int n = blockIdx.x * blockDim.x + threadIdx.x;
    if (n >= N_NODES) return;
    const int r = n / SRANGE, j = n - r * SRANGE;
    float u = 0.f;
    #pragma unroll 8
    for (int bl = 0; bl < NB; ++bl)
        u += partialU[(size_t)(bl * SR + r) * SRANGE + j];
    float di = dinv[n];
    float pre = di * (u + di * s[n]) + c;
    out[n] = 1.f / (1.f + expf(-pre));
}

// ------------------------- fallback path (R1, validated) --------------------
__global__ void wv_kernel(const float* __restrict__ W, const float* __restrict__ b,
                          const float* __restrict__ w2, const float* __restrict__ b2,
                          float* __restrict__ v, float* __restrict__ c) {
    int i = threadIdx.x;
    float acc = 0.f;
    for (int j = 0; j < HIDDEN; ++j) acc += W[i * HIDDEN + j] * w2[j];
    v[i] = acc;
    if (i == 0) {
        float cc = b2[0];
        for (int j = 0; j < HIDDEN; ++j) cc += b[j] * w2[j];
        *c = cc;
    }
}
__global__ void s_kernel(const float* __restrict__ x, const float* __restrict__ v,
                         float* __restrict__ s) {
    const int wave = threadIdx.x >> 6;
    const int lane = threadIdx.x & 63;
    const int n = blockIdx.x * 4 + wave;
    const float4* xr = (const float4*)(x + (size_t)n * IN_DIM);
    const float4* vr = (const float4*)v;
    float4 a  = xr[lane];
    float4 vv = vr[lane];
    float d = a.x * vv.x + a.y * vv.y + a.z * vv.z + a.w * vv.w;
    #pragma unroll
    for (int off = 32; off > 0; off >>= 1) d += __shfl_down(d, off, 64);
    if (lane == 0) s[n] = d;
}
__global__ void deg_kernel(const int* __restrict__ dst, int* __restrict__ cnt) {
    int e = blockIdx.x * blockDim.x + threadIdx.x;
    if (e < N_EDGES) atomicAdd(&cnt[dst[e]], 1);
}
__global__ void dinv_kernel(const int* __restrict__ cnt, const float* __restrict__ s,
                            float* __restrict__ dinv, float* __restrict__ t) {
    int n = blockIdx.x * blockDim.x + threadIdx.x;
    if (n < N_NODES) {
        float di = rsqrtf((float)(cnt[n] + 1));
        dinv[n] = di;
        t[n] = di * s[n];
    }
}
__global__ void scatter_kernel(const int* __restrict__ src, const int* __restrict__ dst,
                               const float* __restrict__ t, float* __restrict__ u) {
    int e = blockIdx.x * blockDim.x + threadIdx.x;
    if (e < N_EDGES) atomicAdd(&u[dst[e]], t[src[e]]);
}
__global__ void final_kernel(const float* __restrict__ dinv, const float* __restrict__ u,
                             const float* __restrict__ s, const float* __restrict__ c,
                             float* __restrict__ out) {
    int n = blockIdx.x * blockDim.x + threadIdx.x;
    if (n < N_NODES) {
        float di = dinv[n];
        float pre = di * (u[n] + di * s[n]) + c[0];
        out[n] = 1.f / (1.f + expf(-pre));
    }
}
// ----------------------------------------------------------------------------

extern "C" void kernel_launch(void* const* d_in, const int* in_sizes, int n_in,
                              void* d_out, int out_size, void* d_ws, size_t ws_size,
                              hipStream_t stream) {
    const float* x   = (const float*)d_in[0];   // [N, 256]
    const int*   ei  = (const int*)  d_in[1];   // [2, E]: src then dst
    const float* W   = (const float*)d_in[2];   // [256, 64]
    const float* b   = (const float*)d_in[3];   // [64]
    const float* w2  = (const float*)d_in[4];   // [64]
    const float* b2  = (const float*)d_in[5];   // [1]
    float* out = (float*)d_out;

    const int* src = ei;
    const int* dst = ei + N_EDGES;

    float* ws   = (float*)d_ws;
    float*    v        = ws + 0;        // 256 (fallback only)
    float*    c        = ws + 256;      // 1   (fallback only)
    float*    s        = ws + 512;      // 100000
    float*    t        = ws + 100608;   // 100000
    float*    dinv     = ws + 200704;   // 100000
    unsigned* partialD = (unsigned*)(ws + 300800);  // 256*3200  =   819,200 words (3.3 MB)
    float*    partialU = ws + 1120000;              // 256*12544 = 3,211,264 floats (12.8 MB)
    const size_t need_bytes = (size_t)(1120000 + 256 * SRANGE) * 4;  // 17.3 MB

    if (ws_size >= need_bytes) {
        fusedA_kernel<<<DEGB + 256, 1024, 0, stream>>>(x, W, w2, (const int4*)dst, partialD, s);
        deg_merge_kernel<<<(N_NODES / 4 + 255) / 256, 256, 0, stream>>>(partialD, s, dinv, t);
        scat_hist_kernel<<<NB * SR, 1024, 0, stream>>>((const int4*)src, (const int4*)dst, t, partialU);
        merge_final_kernel<<<(N_NODES + 511) / 512, 512, 0, stream>>>(partialU, dinv, s, b, w2, b2, out);
    } else {
        // fallback: validated device-atomic path (needs zeroed u/cnt)
        float* u   = ws + 300800;
        int*   cnt = (int*)(ws + 400800);
        hipMemsetAsync((char*)d_ws + (size_t)300800 * 4, 0, (size_t)200000 * 4, stream);
        wv_kernel<<<1, 256, 0, stream>>>(W, b, w2, b2, v, c);
        s_kernel<<<N_NODES / 4, 256, 0, stream>>>(x, v, s);
        deg_kernel<<<(N_EDGES + 255) / 256, 256, 0, stream>>>(dst, cnt);
        dinv_kernel<<<(N_NODES + 255) / 256, 256, 0, stream>>>(cnt, s, dinv, t);
        scatter_kernel<<<(N_EDGES + 255) / 256, 256, 0, stream>>>(src, dst, t, u);
        final_kernel<<<(N_NODES + 255) / 256, 256, 0, stream>>>(dinv, u, s, c, out);
    }
}